// Round 15
// baseline (292.039 us; speedup 1.0000x reference)
//
#include <hip/hip_runtime.h>
#include <stdint.h>

typedef __attribute__((ext_vector_type(4))) int   i32x4_t;   // i8-MFMA operands/acc
typedef __attribute__((ext_vector_type(4))) float f32x4_t;

__device__ __forceinline__ void gload_lds16(const void* g, void* l) {
    __builtin_amdgcn_global_load_lds(
        (__attribute__((address_space(1))) void*)g,
        (__attribute__((address_space(3))) void*)l, 16, 0, 0);
}

// ---------- tiled int8 layout (both A and B) ----------
// 16B chunks: [rowblk256][kt(K/64)][row(256)][c(4)], stored chunk index
// c_sw = c ^ ((row>>1)&3). Each (rowblk,kt) block = 16 KB contiguous ->
// staged linearly via global_load_lds. Frag b128 reads conflict-free
// (verified R10/R12: SQ_LDS_BANK_CONFLICT = 0).

// ---------- pre-pass 1: x fp32 -> int8 per-row dynamic quant ----------
// One block per row. Fast path (K==4096): single-pass, row in registers.

__global__ __launch_bounds__(256) void quant_x_kernel(
    const float* __restrict__ x, uint4* __restrict__ o4,
    float* __restrict__ rowscale, int K, int nkt)
{
    __shared__ float red[256];
    int row = blockIdx.x, tid = threadIdx.x;
    const float4* xr = (const float4*)(x + (size_t)row * K);
    int nch = K >> 4;
    int rb = row & 255;
    int sw = (rb >> 1) & 3;
    size_t blkbase = ((size_t)(row >> 8) * nkt) << 10;

    if (nch == 256) {                       // K==4096: single HBM read
        float4 v[4];
        float lmax = 0.f;
        #pragma unroll
        for (int j = 0; j < 4; ++j) {
            v[j] = xr[tid * 4 + j];
            lmax = fmaxf(lmax, fmaxf(fmaxf(fabsf(v[j].x), fabsf(v[j].y)),
                                     fmaxf(fabsf(v[j].z), fabsf(v[j].w))));
        }
        red[tid] = lmax;
        __syncthreads();
        #pragma unroll
        for (int s = 128; s > 0; s >>= 1) {
            if (tid < s) red[tid] = fmaxf(red[tid], red[tid + s]);
            __syncthreads();
        }
        float rmax = red[0];
        float inv = (rmax > 0.f) ? 127.f / rmax : 0.f;
        if (tid == 0) rowscale[row] = rmax * (1.f / 127.f);

        unsigned u[4];
        #pragma unroll
        for (int j = 0; j < 4; ++j) {
            int q0 = (int)rintf(v[j].x * inv), q1 = (int)rintf(v[j].y * inv);
            int q2 = (int)rintf(v[j].z * inv), q3 = (int)rintf(v[j].w * inv);
            u[j] = (q0 & 255) | ((q1 & 255) << 8) | ((q2 & 255) << 16)
                 | ((unsigned)(q3 & 255) << 24);
        }
        int kt = tid >> 2, cc = tid & 3;
        o4[blkbase + ((size_t)kt << 10) + rb * 4 + (cc ^ sw)] =
            make_uint4(u[0], u[1], u[2], u[3]);
        return;
    }

    float lmax = 0.f;
    for (int c = tid; c < nch; c += 256) {
        #pragma unroll
        for (int j = 0; j < 4; ++j) {
            float4 v = xr[c * 4 + j];
            lmax = fmaxf(lmax, fmaxf(fmaxf(fabsf(v.x), fabsf(v.y)),
                                     fmaxf(fabsf(v.z), fabsf(v.w))));
        }
    }
    red[tid] = lmax;
    __syncthreads();
    #pragma unroll
    for (int s = 128; s > 0; s >>= 1) {
        if (tid < s) red[tid] = fmaxf(red[tid], red[tid + s]);
        __syncthreads();
    }
    float rmax = red[0];
    float inv = (rmax > 0.f) ? 127.f / rmax : 0.f;
    if (tid == 0) rowscale[row] = rmax * (1.f / 127.f);

    for (int c = tid; c < nch; c += 256) {
        unsigned u[4];
        #pragma unroll
        for (int j = 0; j < 4; ++j) {
            float4 v = xr[c * 4 + j];
            int q0 = (int)rintf(v.x * inv), q1 = (int)rintf(v.y * inv);
            int q2 = (int)rintf(v.z * inv), q3 = (int)rintf(v.w * inv);
            u[j] = (q0 & 255) | ((q1 & 255) << 8) | ((q2 & 255) << 16)
                 | ((unsigned)(q3 & 255) << 24);
        }
        int kt = c >> 2, cc = c & 3;
        o4[blkbase + ((size_t)kt << 10) + rb * 4 + (cc ^ sw)] =
            make_uint4(u[0], u[1], u[2], u[3]);
    }
}

// ---------- pre-pass 2: packed int4 (1 byte per int32) -> int8 tiled ----

__global__ __launch_bounds__(256) void quant_w_kernel(
    const int4* __restrict__ pw4, uint4* __restrict__ o4,
    long long nchunks, int cpr /* = K/16 */, int nkt)
{
    long long i = (long long)blockIdx.x * blockDim.x + threadIdx.x;
    if (i >= nchunks) return;
    int r = (int)(i / cpr), c16 = (int)(i - (long long)r * cpr);
    const int4* src = pw4 + ((size_t)r * cpr + c16) * 2;
    int4 v0 = src[0], v1 = src[1];
    int bytes[8] = { v0.x & 255, v0.y & 255, v0.z & 255, v0.w & 255,
                     v1.x & 255, v1.y & 255, v1.z & 255, v1.w & 255 };
    unsigned u[4];
    #pragma unroll
    for (int j = 0; j < 4; ++j) {
        int b0 = bytes[2 * j], b1 = bytes[2 * j + 1];
        int q0 = (b0 & 15) - 8, q1 = ((b0 >> 4) & 15) - 8;
        int q2 = (b1 & 15) - 8, q3 = ((b1 >> 4) & 15) - 8;
        u[j] = (q0 & 255) | ((q1 & 255) << 8) | ((q2 & 255) << 16)
             | ((unsigned)(q3 & 255) << 24);
    }
    int rb = r & 255, kt = c16 >> 2, cc = c16 & 3;
    size_t dst = (((size_t)(r >> 8) * nkt + kt) << 10) + rb * 4
               + (cc ^ ((rb >> 1) & 3));
    o4[dst] = make_uint4(u[0], u[1], u[2], u[3]);
}

// ---------- main GEMM: R10 body + m-half PARITY SKEW ----------------------
// R10 model: GEMM 202us = LDS-pipe 110us + MFMA-pipe 94us running SERIALLY
// (all waves barrier-locked into the same read-then-MFMA rhythm). Fix: split
// the tile body into two m-halves; odd waves process halves in reverse order
// (wave-uniform branch, static acc indices - rule #20). At any instant ~half
// the waves/SIMD are reading LDS while the other half issue MFMA -> the two
// pipes overlap. No layout/sync/traffic change vs R10 (conflict-free
// verified); STAGE & vmcnt(0)+barrier drain identical.

__global__ __launch_bounds__(512, 2) void qlin_gemm256(
    const char* __restrict__ Xq, const char* __restrict__ Wq,
    const float* __restrict__ rowscale,
    const float* __restrict__ scales, const float* __restrict__ bias,
    float* __restrict__ Y, int M, int N, int K)
{
    __shared__ char As[2][16384];
    __shared__ char Bs[2][16384];

    int nbm = M >> 8, nbn = N >> 8, nkt = K >> 6;
    int nwg = nbm * nbn;
    // bijective XCD swizzle (m204 form)
    int bid = blockIdx.x;
    int q8 = nwg >> 3, r8 = nwg & 7;
    int xcd = bid & 7, lid = bid >> 3;
    int wgid = (xcd < r8 ? xcd * (q8 + 1) : r8 * (q8 + 1) + (xcd - r8) * q8) + lid;
    int bm = wgid % nbm, bn = wgid / nbm;

    const char* ga = Xq + (size_t)bm * nkt * 16384;
    const char* gb = Wq + (size_t)bn * nkt * 16384;

    int tid = threadIdx.x, lane = tid & 63, wid = tid >> 6;
    int wr = wid >> 2, wc = wid & 3;          // 2x4 wave grid, per-wave out 128x64
    int fr = lane & 15, fq = lane >> 4;       // frag row / k-chunk (16 int8)
    int csw = fq ^ ((fr >> 1) & 3);           // lane-constant chunk swizzle
    int lsel = fr * 64 + csw * 16;            // byte offset within row group
    int aoff = wr * 8192;                     // wr*128 rows * 64B
    int boff = wc * 4096;                     // wc*64 rows * 64B

    i32x4_t acc[8][4] = {};

#define STAGE(tt)                                                             \
    do {                                                                      \
        int b_ = (tt) & 1;                                                    \
        size_t base_ = (size_t)(tt) * 16384;                                  \
        _Pragma("unroll")                                                     \
        for (int h_ = 0; h_ < 2; ++h_) {                                      \
            gload_lds16(ga + base_ + h_ * 8192 + tid * 16,                    \
                        &As[b_][h_ * 8192 + wid * 1024]);                     \
            gload_lds16(gb + base_ + h_ * 8192 + tid * 16,                    \
                        &Bs[b_][h_ * 8192 + wid * 1024]);                     \
        }                                                                     \
    } while (0)

// one m-half: read 4 A frags (static base mb_), 16 MFMA into acc[mb_+m][n]
#define HALF(mb_)                                                             \
    do {                                                                      \
        i32x4_t a_[4];                                                        \
        _Pragma("unroll")                                                     \
        for (int m_ = 0; m_ < 4; ++m_)                                        \
            a_[m_] = *(const i32x4_t*)&Ab[aoff + ((mb_) + m_) * 1024 + lsel]; \
        __builtin_amdgcn_s_setprio(1);                                        \
        _Pragma("unroll")                                                     \
        for (int m_ = 0; m_ < 4; ++m_)                                        \
            _Pragma("unroll")                                                 \
            for (int n_ = 0; n_ < 4; ++n_)                                    \
                acc[(mb_) + m_][n_] = __builtin_amdgcn_mfma_i32_16x16x64_i8(  \
                    a_[m_], b[n_], acc[(mb_) + m_][n_], 0, 0, 0);             \
        __builtin_amdgcn_s_setprio(0);                                        \
    } while (0)

    // prologue: stage tile 0
    STAGE(0);

    int nt = nkt;
    for (int t = 0; t < nt; ++t) {
        asm volatile("s_waitcnt vmcnt(0)" ::: "memory");
        __builtin_amdgcn_s_barrier();
        __builtin_amdgcn_sched_barrier(0);

        const char* Ab = &As[t & 1][0];
        const char* Bb = &Bs[t & 1][0];

        i32x4_t b[4];
        #pragma unroll
        for (int n = 0; n < 4; ++n)
            b[n] = *(const i32x4_t*)&Bb[boff + n * 1024 + lsel];

        if (t + 1 < nt) STAGE(t + 1);

        if (wid & 1) { HALF(4); HALF(0); }   // odd waves: high half first
        else         { HALF(0); HALF(4); }   // even waves: low half first
    }
#undef STAGE
#undef HALF

    int row_base = bm * 256 + wr * 128;
    int col_base = bn * 256 + wc * 64;
    float rs[8][4];
    #pragma unroll
    for (int m = 0; m < 8; ++m)
        #pragma unroll
        for (int r2 = 0; r2 < 4; ++r2)
            rs[m][r2] = rowscale[row_base + m * 16 + fq * 4 + r2];
    #pragma unroll
    for (int n = 0; n < 4; ++n) {
        int col = col_base + n * 16 + fr;
        float sc = scales[col], bi = bias[col];
        #pragma unroll
        for (int m = 0; m < 8; ++m) {
            int m0 = row_base + m * 16 + fq * 4;
            #pragma unroll
            for (int r2 = 0; r2 < 4; ++r2)
                Y[(size_t)(m0 + r2) * N + col] =
                    (float)acc[m][n][r2] * (rs[m][r2] * sc) + bi;
        }
    }
}

// ---------- fallback (if ws too small / odd dims): tiled fp32, inline dequant --

__global__ __launch_bounds__(256) void qlin_fallback(
    const float* __restrict__ x, const int* __restrict__ pw,
    const float* __restrict__ scales, const float* __restrict__ bias,
    float* __restrict__ Y, int M, int N, int K)
{
    __shared__ float Xs[64][32];
    __shared__ float Ws[64][33];
    int bn = blockIdx.x, bm = blockIdx.y;
    int tid = threadIdx.x;
    int tr = tid >> 4, tc = tid & 15;
    float acc[4][4] = {};
    int K2 = K >> 1;
    for (int kt = 0; kt < K; kt += 32) {
        #pragma unroll
        for (int u = 0; u < 8; ++u) {
            int idx = u * 256 + tid;
            int rr = idx >> 5, cc = idx & 31;
            Xs[rr][cc] = x[(size_t)(bm * 64 + rr) * K + kt + cc];
        }
        #pragma unroll
        for (int u = 0; u < 4; ++u) {
            int idx = u * 256 + tid;
            int rr = idx >> 4, cc = idx & 15;
            int v = pw[(size_t)(bn * 64 + rr) * K2 + (kt >> 1) + cc];
            Ws[rr][cc * 2]     = (float)((v & 15) - 8);
            Ws[rr][cc * 2 + 1] = (float)(((v >> 4) & 15) - 8);
        }
        __syncthreads();
        #pragma unroll 8
        for (int kk = 0; kk < 32; ++kk) {
            float xv[4], wv[4];
            #pragma unroll
            for (int i = 0; i < 4; ++i) xv[i] = Xs[tr * 4 + i][kk];
            #pragma unroll
            for (int j = 0; j < 4; ++j) wv[j] = Ws[tc * 4 + j][kk];
            #pragma unroll
            for (int i = 0; i < 4; ++i)
                #pragma unroll
                for (int j = 0; j < 4; ++j)
                    acc[i][j] += xv[i] * wv[j];
        }
        __syncthreads();
    }
    #pragma unroll
    for (int j = 0; j < 4; ++j) {
        int n = bn * 64 + tc * 4 + j;
        float sc = scales[n], bi = bias[n];
        #pragma unroll
        for (int i = 0; i < 4; ++i) {
            int m = bm * 64 + tr * 4 + i;
            Y[(size_t)m * N + n] = acc[i][j] * sc + bi;
        }
    }
}

// ---------- host ----------

extern "C" void kernel_launch(void* const* d_in, const int* in_sizes, int n_in,
                              void* d_out, int out_size, void* d_ws, size_t ws_size,
                              hipStream_t stream) {
    const float* x      = (const float*)d_in[0];
    const int*   pw     = (const int*)d_in[1];
    const float* scales = (const float*)d_in[2];
    const float* bias   = (const float*)d_in[3];
    float*       y      = (float*)d_out;

    int N = in_sizes[2];                         // 11008
    long long pwe = in_sizes[1];                 // N*K/2 (int32 elems, 1 byte each)
    int K = (int)((2 * pwe) / N);                // 4096
    int M = in_sizes[0] / K;                     // 4096

    size_t xq_bytes = (size_t)M * K;             // int8 A
    size_t wq_bytes = (size_t)N * K;             // int8 W
    size_t rs_bytes = (size_t)M * 4;             // rowscale

    bool fits = (ws_size >= xq_bytes + wq_bytes + rs_bytes);
    bool dims_ok = (M % 256 == 0) && (N % 256 == 0) && (K % 64 == 0) && (K >= 128);

    if (fits && dims_ok) {
        char*  xq = (char*)d_ws;
        char*  wq = (char*)d_ws + xq_bytes;
        float* rs = (float*)((char*)d_ws + xq_bytes + wq_bytes);
        int nkt = K / 64;
        hipLaunchKernelGGL(quant_x_kernel, dim3(M), dim3(256), 0, stream,
                           x, (uint4*)xq, rs, K, nkt);
        long long wchunks = (long long)N * (K / 16);
        int wblocks = (int)((wchunks + 255) / 256);
        hipLaunchKernelGGL(quant_w_kernel, dim3(wblocks), dim3(256), 0, stream,
                           (const int4*)pw, (uint4*)wq, wchunks, K / 16, nkt);
        int nwg = (M / 256) * (N / 256);
        hipLaunchKernelGGL(qlin_gemm256, dim3(nwg), dim3(512), 0, stream,
                           xq, wq, rs, scales, bias, y, M, N, K);
    } else {
        hipLaunchKernelGGL(qlin_fallback, dim3(N / 64, M / 64), dim3(256), 0, stream,
                           x, pw, scales, bias, y, M, N, K);
    }
}

// Round 16
// 238.731 us; speedup vs baseline: 1.2233x; 1.2233x over previous
//
#include <hip/hip_runtime.h>
#include <stdint.h>

typedef __attribute__((ext_vector_type(4))) int   i32x4_t;   // i8-MFMA operands/acc
typedef __attribute__((ext_vector_type(4))) float f32x4_t;

__device__ __forceinline__ void gload_lds16(const void* g, void* l) {
    __builtin_amdgcn_global_load_lds(
        (__attribute__((address_space(1))) void*)g,
        (__attribute__((address_space(3))) void*)l, 16, 0, 0);
}

// ---------- tiled int8 layout (both A and B) ----------
// 16B chunks: [rowblk256][kt(K/64)][row(256)][c(4)], stored chunk index
// c_sw = c ^ ((row>>1)&3). Each (rowblk,kt) block = 16 KB contiguous ->
// staged linearly via global_load_lds. Frag b128 reads conflict-free
// (verified R10/R12: SQ_LDS_BANK_CONFLICT = 0).

// ---------- pre-pass 1: x fp32 -> int8 per-row dynamic quant ----------
// One block per row. Fast path (K==4096): single-pass, row in registers
// (verified R12/R14/R15: absmax identical to two-pass).

__global__ __launch_bounds__(256) void quant_x_kernel(
    const float* __restrict__ x, uint4* __restrict__ o4,
    float* __restrict__ rowscale, int K, int nkt)
{
    __shared__ float red[256];
    int row = blockIdx.x, tid = threadIdx.x;
    const float4* xr = (const float4*)(x + (size_t)row * K);
    int nch = K >> 4;
    int rb = row & 255;
    int sw = (rb >> 1) & 3;
    size_t blkbase = ((size_t)(row >> 8) * nkt) << 10;

    if (nch == 256) {                       // K==4096: single HBM read
        float4 v[4];
        float lmax = 0.f;
        #pragma unroll
        for (int j = 0; j < 4; ++j) {
            v[j] = xr[tid * 4 + j];
            lmax = fmaxf(lmax, fmaxf(fmaxf(fabsf(v[j].x), fabsf(v[j].y)),
                                     fmaxf(fabsf(v[j].z), fabsf(v[j].w))));
        }
        red[tid] = lmax;
        __syncthreads();
        #pragma unroll
        for (int s = 128; s > 0; s >>= 1) {
            if (tid < s) red[tid] = fmaxf(red[tid], red[tid + s]);
            __syncthreads();
        }
        float rmax = red[0];
        float inv = (rmax > 0.f) ? 127.f / rmax : 0.f;
        if (tid == 0) rowscale[row] = rmax * (1.f / 127.f);

        unsigned u[4];
        #pragma unroll
        for (int j = 0; j < 4; ++j) {
            int q0 = (int)rintf(v[j].x * inv), q1 = (int)rintf(v[j].y * inv);
            int q2 = (int)rintf(v[j].z * inv), q3 = (int)rintf(v[j].w * inv);
            u[j] = (q0 & 255) | ((q1 & 255) << 8) | ((q2 & 255) << 16)
                 | ((unsigned)(q3 & 255) << 24);
        }
        int kt = tid >> 2, cc = tid & 3;
        o4[blkbase + ((size_t)kt << 10) + rb * 4 + (cc ^ sw)] =
            make_uint4(u[0], u[1], u[2], u[3]);
        return;
    }

    float lmax = 0.f;
    for (int c = tid; c < nch; c += 256) {
        #pragma unroll
        for (int j = 0; j < 4; ++j) {
            float4 v = xr[c * 4 + j];
            lmax = fmaxf(lmax, fmaxf(fmaxf(fabsf(v.x), fabsf(v.y)),
                                     fmaxf(fabsf(v.z), fabsf(v.w))));
        }
    }
    red[tid] = lmax;
    __syncthreads();
    #pragma unroll
    for (int s = 128; s > 0; s >>= 1) {
        if (tid < s) red[tid] = fmaxf(red[tid], red[tid + s]);
        __syncthreads();
    }
    float rmax = red[0];
    float inv = (rmax > 0.f) ? 127.f / rmax : 0.f;
    if (tid == 0) rowscale[row] = rmax * (1.f / 127.f);

    for (int c = tid; c < nch; c += 256) {
        unsigned u[4];
        #pragma unroll
        for (int j = 0; j < 4; ++j) {
            float4 v = xr[c * 4 + j];
            int q0 = (int)rintf(v.x * inv), q1 = (int)rintf(v.y * inv);
            int q2 = (int)rintf(v.z * inv), q3 = (int)rintf(v.w * inv);
            u[j] = (q0 & 255) | ((q1 & 255) << 8) | ((q2 & 255) << 16)
                 | ((unsigned)(q3 & 255) << 24);
        }
        int kt = c >> 2, cc = c & 3;
        o4[blkbase + ((size_t)kt << 10) + rb * 4 + (cc ^ sw)] =
            make_uint4(u[0], u[1], u[2], u[3]);
    }
}

// ---------- pre-pass 2: packed int4 (1 byte per int32) -> int8 tiled ----

__global__ __launch_bounds__(256) void quant_w_kernel(
    const int4* __restrict__ pw4, uint4* __restrict__ o4,
    long long nchunks, int cpr /* = K/16 */, int nkt)
{
    long long i = (long long)blockIdx.x * blockDim.x + threadIdx.x;
    if (i >= nchunks) return;
    int r = (int)(i / cpr), c16 = (int)(i - (long long)r * cpr);
    const int4* src = pw4 + ((size_t)r * cpr + c16) * 2;
    int4 v0 = src[0], v1 = src[1];
    int bytes[8] = { v0.x & 255, v0.y & 255, v0.z & 255, v0.w & 255,
                     v1.x & 255, v1.y & 255, v1.z & 255, v1.w & 255 };
    unsigned u[4];
    #pragma unroll
    for (int j = 0; j < 4; ++j) {
        int b0 = bytes[2 * j], b1 = bytes[2 * j + 1];
        int q0 = (b0 & 15) - 8, q1 = ((b0 >> 4) & 15) - 8;
        int q2 = (b1 & 15) - 8, q3 = ((b1 >> 4) & 15) - 8;
        u[j] = (q0 & 255) | ((q1 & 255) << 8) | ((q2 & 255) << 16)
             | ((unsigned)(q3 & 255) << 24);
    }
    int rb = r & 255, kt = c16 >> 2, cc = c16 & 3;
    size_t dst = (((size_t)(r >> 8) * nkt + kt) << 10) + rb * 4
               + (cc ^ ((rb >> 1) & 3));
    o4[dst] = make_uint4(u[0], u[1], u[2], u[3]);
}

// ---------- main GEMM: 256x256x64 int8, R10 loose schedule (TERMINAL) ----
// EXACT R10 body (202us GEMM, 1827 TOPS = 46% of i8 ceiling, verified best).
// Per tile t (ONE sync point): vmcnt(0) [staging issued mid-body t-1, long
// in flight] -> s_barrier -> sched_barrier(0) -> 12 frag b128 reads ->
// STAGE(t+1) (4 DMA) -> 32 mfma_i32_16x16x64_i8 with compiler-managed lgkm
// interleave. Schedule variants R3/R5/R7/R8/R9/R15 and traffic variants
// R12/R14 all regressed vs this body - do not restructure it.

__global__ __launch_bounds__(512, 2) void qlin_gemm256(
    const char* __restrict__ Xq, const char* __restrict__ Wq,
    const float* __restrict__ rowscale,
    const float* __restrict__ scales, const float* __restrict__ bias,
    float* __restrict__ Y, int M, int N, int K)
{
    __shared__ char As[2][16384];
    __shared__ char Bs[2][16384];

    int nbm = M >> 8, nbn = N >> 8, nkt = K >> 6;
    int nwg = nbm * nbn;
    // bijective XCD swizzle (m204 form)
    int bid = blockIdx.x;
    int q8 = nwg >> 3, r8 = nwg & 7;
    int xcd = bid & 7, lid = bid >> 3;
    int wgid = (xcd < r8 ? xcd * (q8 + 1) : r8 * (q8 + 1) + (xcd - r8) * q8) + lid;
    int bm = wgid % nbm, bn = wgid / nbm;

    const char* ga = Xq + (size_t)bm * nkt * 16384;
    const char* gb = Wq + (size_t)bn * nkt * 16384;

    int tid = threadIdx.x, lane = tid & 63, wid = tid >> 6;
    int wr = wid >> 2, wc = wid & 3;          // 2x4 wave grid, per-wave out 128x64
    int fr = lane & 15, fq = lane >> 4;       // frag row / k-chunk (16 int8)
    int csw = fq ^ ((fr >> 1) & 3);           // lane-constant chunk swizzle
    int lsel = fr * 64 + csw * 16;            // byte offset within 16KB tile
    int aoff = wr * 8192;                     // wr*128 rows * 64B
    int boff = wc * 4096;                     // wc*64 rows * 64B

    i32x4_t acc[8][4] = {};

#define STAGE(tt)                                                             \
    do {                                                                      \
        int b_ = (tt) & 1;                                                    \
        size_t base_ = (size_t)(tt) * 16384;                                  \
        _Pragma("unroll")                                                     \
        for (int h_ = 0; h_ < 2; ++h_) {                                      \
            gload_lds16(ga + base_ + h_ * 8192 + tid * 16,                    \
                        &As[b_][h_ * 8192 + wid * 1024]);                     \
            gload_lds16(gb + base_ + h_ * 8192 + tid * 16,                    \
                        &Bs[b_][h_ * 8192 + wid * 1024]);                     \
        }                                                                     \
    } while (0)

    // prologue: stage tile 0
    STAGE(0);

    int nt = nkt;
    for (int t = 0; t < nt; ++t) {
        asm volatile("s_waitcnt vmcnt(0)" ::: "memory");
        __builtin_amdgcn_s_barrier();
        __builtin_amdgcn_sched_barrier(0);

        const char* Ab = &As[t & 1][0];
        const char* Bb = &Bs[t & 1][0];

        i32x4_t a[8], b[4];
        #pragma unroll
        for (int n = 0; n < 4; ++n)
            b[n] = *(const i32x4_t*)&Bb[boff + n * 1024 + lsel];
        #pragma unroll
        for (int m = 0; m < 8; ++m)
            a[m] = *(const i32x4_t*)&Ab[aoff + m * 1024 + lsel];

        if (t + 1 < nt) STAGE(t + 1);

        __builtin_amdgcn_s_setprio(1);
        #pragma unroll
        for (int m = 0; m < 8; ++m)
            #pragma unroll
            for (int n = 0; n < 4; ++n)
                acc[m][n] = __builtin_amdgcn_mfma_i32_16x16x64_i8(
                    a[m], b[n], acc[m][n], 0, 0, 0);
        __builtin_amdgcn_s_setprio(0);
    }
#undef STAGE

    int row_base = bm * 256 + wr * 128;
    int col_base = bn * 256 + wc * 64;
    float rs[8][4];
    #pragma unroll
    for (int m = 0; m < 8; ++m)
        #pragma unroll
        for (int r2 = 0; r2 < 4; ++r2)
            rs[m][r2] = rowscale[row_base + m * 16 + fq * 4 + r2];
    #pragma unroll
    for (int n = 0; n < 4; ++n) {
        int col = col_base + n * 16 + fr;
        float sc = scales[col], bi = bias[col];
        #pragma unroll
        for (int m = 0; m < 8; ++m) {
            int m0 = row_base + m * 16 + fq * 4;
            #pragma unroll
            for (int r2 = 0; r2 < 4; ++r2)
                Y[(size_t)(m0 + r2) * N + col] =
                    (float)acc[m][n][r2] * (rs[m][r2] * sc) + bi;
        }
    }
}

// ---------- fallback (if ws too small / odd dims): tiled fp32, inline dequant --

__global__ __launch_bounds__(256) void qlin_fallback(
    const float* __restrict__ x, const int* __restrict__ pw,
    const float* __restrict__ scales, const float* __restrict__ bias,
    float* __restrict__ Y, int M, int N, int K)
{
    __shared__ float Xs[64][32];
    __shared__ float Ws[64][33];
    int bn = blockIdx.x, bm = blockIdx.y;
    int tid = threadIdx.x;
    int tr = tid >> 4, tc = tid & 15;
    float acc[4][4] = {};
    int K2 = K >> 1;
    for (int kt = 0; kt < K; kt += 32) {
        #pragma unroll
        for (int u = 0; u < 8; ++u) {
            int idx = u * 256 + tid;
            int rr = idx >> 5, cc = idx & 31;
            Xs[rr][cc] = x[(size_t)(bm * 64 + rr) * K + kt + cc];
        }
        #pragma unroll
        for (int u = 0; u < 4; ++u) {
            int idx = u * 256 + tid;
            int rr = idx >> 4, cc = idx & 15;
            int v = pw[(size_t)(bn * 64 + rr) * K2 + (kt >> 1) + cc];
            Ws[rr][cc * 2]     = (float)((v & 15) - 8);
            Ws[rr][cc * 2 + 1] = (float)(((v >> 4) & 15) - 8);
        }
        __syncthreads();
        #pragma unroll 8
        for (int kk = 0; kk < 32; ++kk) {
            float xv[4], wv[4];
            #pragma unroll
            for (int i = 0; i < 4; ++i) xv[i] = Xs[tr * 4 + i][kk];
            #pragma unroll
            for (int j = 0; j < 4; ++j) wv[j] = Ws[tc * 4 + j][kk];
            #pragma unroll
            for (int i = 0; i < 4; ++i)
                #pragma unroll
                for (int j = 0; j < 4; ++j)
                    acc[i][j] += xv[i] * wv[j];
        }
        __syncthreads();
    }
    #pragma unroll
    for (int j = 0; j < 4; ++j) {
        int n = bn * 64 + tc * 4 + j;
        float sc = scales[n], bi = bias[n];
        #pragma unroll
        for (int i = 0; i < 4; ++i) {
            int m = bm * 64 + tr * 4 + i;
            Y[(size_t)m * N + n] = acc[i][j] * sc + bi;
        }
    }
}

// ---------- host ----------

extern "C" void kernel_launch(void* const* d_in, const int* in_sizes, int n_in,
                              void* d_out, int out_size, void* d_ws, size_t ws_size,
                              hipStream_t stream) {
    const float* x      = (const float*)d_in[0];
    const int*   pw     = (const int*)d_in[1];
    const float* scales = (const float*)d_in[2];
    const float* bias   = (const float*)d_in[3];
    float*       y      = (float*)d_out;

    int N = in_sizes[2];                         // 11008
    long long pwe = in_sizes[1];                 // N*K/2 (int32 elems, 1 byte each)
    int K = (int)((2 * pwe) / N);                // 4096
    int M = in_sizes[0] / K;                     // 4096

    size_t xq_bytes = (size_t)M * K;             // int8 A
    size_t wq_bytes = (size_t)N * K;             // int8 W
    size_t rs_bytes = (size_t)M * 4;             // rowscale

    bool fits = (ws_size >= xq_bytes + wq_bytes + rs_bytes);
    bool dims_ok = (M % 256 == 0) && (N % 256 == 0) && (K % 64 == 0) && (K >= 128);

    if (fits && dims_ok) {
        char*  xq = (char*)d_ws;
        char*  wq = (char*)d_ws + xq_bytes;
        float* rs = (float*)((char*)d_ws + xq_bytes + wq_bytes);
        int nkt = K / 64;
        hipLaunchKernelGGL(quant_x_kernel, dim3(M), dim3(256), 0, stream,
                           x, (uint4*)xq, rs, K, nkt);
        long long wchunks = (long long)N * (K / 16);
        int wblocks = (int)((wchunks + 255) / 256);
        hipLaunchKernelGGL(quant_w_kernel, dim3(wblocks), dim3(256), 0, stream,
                           (const int4*)pw, (uint4*)wq, wchunks, K / 16, nkt);
        int nwg = (M / 256) * (N / 256);
        hipLaunchKernelGGL(qlin_gemm256, dim3(nwg), dim3(512), 0, stream,
                           xq, wq, rs, scales, bias, y, M, N, K);
    } else {
        hipLaunchKernelGGL(qlin_fallback, dim3(N / 64, M / 64), dim3(256), 0, stream,
                           x, pw, scales, bias, y, M, N, K);
    }
}